// Round 3
// baseline (1886.313 us; speedup 1.0000x reference)
//
#include <hip/hip_runtime.h>

#define B_ROWS 262144
#define ZDIM   128
#define ZHALF  64
#define HS     50
#define NFLOW  2
#define RPB    128   // rows per block (256 threads = 2 waves x 2 col-groups)
#define HSTR   52    // h row stride (floats): 208 B, 16B-aligned, b128 conflict-free
#define SSTR   36    // staging row stride (floats): 144 B, 16B-aligned, b128 conflict-free

__device__ __forceinline__ float frcp_(float x) { return __builtin_amdgcn_rcpf(x); }

__device__ __forceinline__ float tanh_fast(float x) {
    // tanh(x) = 1 - 2/(1+e^{2x}); exact at +-inf, ~1e-7 abs error
    float e = __expf(2.0f * x);
    return 1.0f - 2.0f * frcp_(e + 1.0f);
}

__device__ __forceinline__ float sigmoid_fast(float x) {
    return frcp_(1.0f + __expf(-x));
}

// ---------------------------------------------------------------------------
// Setup kernel: transpose W_mu / W_sig from [f][j(64)][k(50)] to
// [f][k(50)][j(64)] so phase-2 scalar (broadcast) loads are contiguous rows.
// ---------------------------------------------------------------------------
extern "C" __global__ void transpose_w(const float* __restrict__ Wmu,
                                       const float* __restrict__ Wsig,
                                       float* __restrict__ wt)
{
    int idx = blockIdx.x * 256 + threadIdx.x;
    const int TOT = NFLOW * 2 * ZHALF * HS;   // 12800
    if (idx >= TOT) return;
    int f   = idx / (ZHALF * HS);
    int rem = idx - f * (ZHALF * HS);
    int j   = rem / HS;
    int k   = rem - j * HS;
    int o   = f * (ZHALF * HS) + k * ZHALF + j;
    wt[o]        = Wmu[idx];
    wt[TOT + o]  = Wsig[idx];
}

// 4 partial dot products over a 32-element register slice (2 accums each)
#define DOT32x4(INR, WR0, WR1, WR2, WR3, R0, R1, R2, R3)                     \
{                                                                            \
    float a0 = 0.f, c0 = 0.f, a1 = 0.f, c1 = 0.f;                            \
    float a2 = 0.f, c2_ = 0.f, a3 = 0.f, c3 = 0.f;                           \
    _Pragma("unroll")                                                        \
    for (int kk = 0; kk < 32; kk += 2) {                                     \
        float xe = INR[kk], xo = INR[kk + 1];                                \
        a0  = __builtin_fmaf(xe, WR0[kk],     a0);                           \
        c0  = __builtin_fmaf(xo, WR0[kk + 1], c0);                           \
        a1  = __builtin_fmaf(xe, WR1[kk],     a1);                           \
        c1  = __builtin_fmaf(xo, WR1[kk + 1], c1);                           \
        a2  = __builtin_fmaf(xe, WR2[kk],     a2);                           \
        c2_ = __builtin_fmaf(xo, WR2[kk + 1], c2_);                          \
        a3  = __builtin_fmaf(xe, WR3[kk],     a3);                           \
        c3  = __builtin_fmaf(xo, WR3[kk + 1], c3);                           \
    }                                                                        \
    R0 = a0 + c0; R1 = a1 + c1; R2 = a2 + c2_; R3 = a3 + c3;                 \
}

#define DOT32x2(INR, WR0, WR1, R0, R1)                                       \
{                                                                            \
    float a0 = 0.f, c0 = 0.f, a1 = 0.f, c1 = 0.f;                            \
    _Pragma("unroll")                                                        \
    for (int kk = 0; kk < 32; kk += 2) {                                     \
        float xe = INR[kk], xo = INR[kk + 1];                                \
        a0 = __builtin_fmaf(xe, WR0[kk],     a0);                            \
        c0 = __builtin_fmaf(xo, WR0[kk + 1], c0);                            \
        a1 = __builtin_fmaf(xe, WR1[kk],     a1);                            \
        c1 = __builtin_fmaf(xo, WR1[kk + 1], c1);                            \
    }                                                                        \
    R0 = a0 + c0; R1 = a1 + c1;                                              \
}

// ---------------------------------------------------------------------------
// One coupling. Each thread owns a 32-col slice (col-group g) of both z
// halves. Phase 1 (h = tanh(W0 @ zin + b0)) is split: partial dots over the
// thread's 32-k slice; partner partials exchanged through the LDS h-row with
// a j-split two-pass (SET0 = j 0..23 + {48,49}, SET1 = j 24..47).
// Phase 2: fused sig+mu accumulation, 16-wide chunks, h read back as float4.
// Weights are wave-uniform (g is constant per wave) -> scalar s_load.
// ---------------------------------------------------------------------------
#define COUPLING(INR, OUTR, I01)                                             \
{                                                                            \
    const float* W0c = W_in + (I01) * (HS * ZHALF) + g * 32;                 \
    const float* b0c = b_in + (I01) * HS;                                    \
    /* pass 1: my j-set, own-k partials -> LDS */                            \
    {                                                                        \
        const int jb = g * 24;                                               \
        _Pragma("unroll 1")                                                  \
        for (int jq = 0; jq < 24; jq += 4) {                                 \
            const float* wr0 = W0c + (jb + jq + 0) * ZHALF;                  \
            const float* wr1 = W0c + (jb + jq + 1) * ZHALF;                  \
            const float* wr2 = W0c + (jb + jq + 2) * ZHALF;                  \
            const float* wr3 = W0c + (jb + jq + 3) * ZHALF;                  \
            float4 pp;                                                       \
            DOT32x4(INR, wr0, wr1, wr2, wr3, pp.x, pp.y, pp.z, pp.w)         \
            *reinterpret_cast<float4*>(hrow + jb + jq) = pp;                 \
        }                                                                    \
        if (g == 0) {                                                        \
            const float* wr0 = W0c + 48 * ZHALF;                             \
            const float* wr1 = W0c + 49 * ZHALF;                             \
            float2 pp;                                                       \
            DOT32x2(INR, wr0, wr1, pp.x, pp.y)                               \
            *reinterpret_cast<float2*>(hrow + 48) = pp;                      \
        }                                                                    \
    }                                                                        \
    __syncthreads();                                                         \
    /* pass 2: partner j-set: partner partial + own partial + bias, tanh */  \
    {                                                                        \
        const int jb = (1 - g) * 24;                                         \
        _Pragma("unroll 1")                                                  \
        for (int jq = 0; jq < 24; jq += 4) {                                 \
            const float* wr0 = W0c + (jb + jq + 0) * ZHALF;                  \
            const float* wr1 = W0c + (jb + jq + 1) * ZHALF;                  \
            const float* wr2 = W0c + (jb + jq + 2) * ZHALF;                  \
            const float* wr3 = W0c + (jb + jq + 3) * ZHALF;                  \
            float4 pp = *reinterpret_cast<const float4*>(hrow + jb + jq);    \
            float r0, r1, r2, r3;                                            \
            DOT32x4(INR, wr0, wr1, wr2, wr3, r0, r1, r2, r3)                 \
            float4 hv;                                                       \
            hv.x = tanh_fast(pp.x + r0 + b0c[jb + jq + 0]);                  \
            hv.y = tanh_fast(pp.y + r1 + b0c[jb + jq + 1]);                  \
            hv.z = tanh_fast(pp.z + r2 + b0c[jb + jq + 2]);                  \
            hv.w = tanh_fast(pp.w + r3 + b0c[jb + jq + 3]);                  \
            *reinterpret_cast<float4*>(hrow + jb + jq) = hv;                 \
        }                                                                    \
        if (g == 1) {                                                        \
            const float* wr0 = W0c + 48 * ZHALF;                             \
            const float* wr1 = W0c + 49 * ZHALF;                             \
            float2 pp = *reinterpret_cast<const float2*>(hrow + 48);         \
            float r0, r1;                                                    \
            DOT32x2(INR, wr0, wr1, r0, r1)                                   \
            float2 hv;                                                       \
            hv.x = tanh_fast(pp.x + r0 + b0c[48]);                           \
            hv.y = tanh_fast(pp.y + r1 + b0c[49]);                           \
            *reinterpret_cast<float2*>(hrow + 48) = hv;                      \
        }                                                                    \
    }                                                                        \
    __syncthreads();                                                         \
    /* phase 2: fused sig+mu, 16-wide chunks over thread's 32 out cols */    \
    const float* WTsc = WTsig + (I01) * (HS * ZHALF) + g * 32;               \
    const float* WTmc = WTmu  + (I01) * (HS * ZHALF) + g * 32;               \
    const float* bsc  = b_sig + (I01) * ZHALF + g * 32;                      \
    const float* bmc  = b_mu  + (I01) * ZHALF + g * 32;                      \
    _Pragma("unroll")                                                        \
    for (int c2 = 0; c2 < 2; ++c2) {                                         \
        float accS[16], accM[16];                                            \
        _Pragma("unroll")                                                    \
        for (int j = 0; j < 16; ++j) { accS[j] = 0.f; accM[j] = 0.f; }       \
        _Pragma("unroll 1")                                                  \
        for (int k4 = 0; k4 < 48; k4 += 4) {                                 \
            float4 hq = *reinterpret_cast<const float4*>(hrow + k4);         \
            _Pragma("unroll")                                                \
            for (int kk = 0; kk < 4; ++kk) {                                 \
                float hv = (kk == 0) ? hq.x : (kk == 1) ? hq.y               \
                         : (kk == 2) ? hq.z : hq.w;                          \
                const float* ws = WTsc + (k4 + kk) * ZHALF + c2 * 16;        \
                const float* wm = WTmc + (k4 + kk) * ZHALF + c2 * 16;        \
                _Pragma("unroll")                                            \
                for (int j = 0; j < 16; ++j) {                               \
                    accS[j] = __builtin_fmaf(hv, ws[j], accS[j]);            \
                    accM[j] = __builtin_fmaf(hv, wm[j], accM[j]);            \
                }                                                            \
            }                                                                \
        }                                                                    \
        {                                                                    \
            float2 ht = *reinterpret_cast<const float2*>(hrow + 48);         \
            const float* ws0 = WTsc + 48 * ZHALF + c2 * 16;                  \
            const float* ws1 = WTsc + 49 * ZHALF + c2 * 16;                  \
            const float* wm0 = WTmc + 48 * ZHALF + c2 * 16;                  \
            const float* wm1 = WTmc + 49 * ZHALF + c2 * 16;                  \
            _Pragma("unroll")                                                \
            for (int j = 0; j < 16; ++j) {                                   \
                accS[j] = __builtin_fmaf(ht.x, ws0[j], accS[j]);             \
                accS[j] = __builtin_fmaf(ht.y, ws1[j], accS[j]);             \
                accM[j] = __builtin_fmaf(ht.x, wm0[j], accM[j]);             \
                accM[j] = __builtin_fmaf(ht.y, wm1[j], accM[j]);             \
            }                                                                \
        }                                                                    \
        _Pragma("unroll")                                                    \
        for (int j = 0; j < 16; ++j) {                                       \
            float sg  = sigmoid_fast(accS[j] + bsc[c2 * 16 + j]);            \
            float muv = accM[j] + bmc[c2 * 16 + j];                          \
            OUTR[c2 * 16 + j] = __builtin_fmaf(OUTR[c2 * 16 + j], sg, muv);  \
            float lg = __logf(sg);                                           \
            if ((j & 3) == 0)      ld0 += lg;                                \
            else if ((j & 3) == 1) ld1 += lg;                                \
            else if ((j & 3) == 2) ld2 += lg;                                \
            else                   ld3 += lg;                                \
        }                                                                    \
    }                                                                        \
    __syncthreads();                                                         \
}

// ---------------------------------------------------------------------------
// Main kernel: 128 rows / 256 threads. Thread (r, g) owns cols [g*32,g*32+32)
// of z1 (zA) and z2 (zB): 64 persistent VGPRs, peak demand ~112 -> fits the
// 128-VGPR tier with NO spills (rounds 0-2 spilled ~500 MB at demand ~180).
// LDS 26.6 KB (h rows, stride 52) -> 16 waves/CU (50% occupancy).
// ---------------------------------------------------------------------------
extern "C" __global__ __launch_bounds__(256) void flow_main(
    const float* __restrict__ mean, const float* __restrict__ logvar,
    const float* __restrict__ eps,  const float* __restrict__ W_in,
    const float* __restrict__ b_in, const float* __restrict__ b_mu,
    const float* __restrict__ b_sig,const float* __restrict__ WTmu,
    const float* __restrict__ WTsig, float* __restrict__ out)
{
    __shared__ float smem[RPB * HSTR];          // 26624 B

    const int tid  = threadIdx.x;
    const int wid  = tid >> 6;
    const int lane = tid & 63;
    const int g    = wid >> 1;                  // col-group (uniform per wave)
    const int r    = ((wid & 1) << 6) | lane;   // row within block, 0..127
    const int row0 = blockIdx.x * RPB;

    float zA[32], zB[32];
    float qsum = 0.f;

    // ---- Phase A: float4 coalesced load, z = eps*exp(0.5 lv)+mean,
    //      32-col staging transpose; q = eps^2 + logvar summed per slice ----
    const int col4 = (tid & 7) * 4;             // 0..28
    const int rowb = tid >> 3;                  // 0..31
    float* zs = smem;                           // [128][36] staging
    #pragma unroll
    for (int c = 0; c < 4; ++c) {
        float4 q4s[4];
        #pragma unroll
        for (int s = 0; s < 4; ++s) {
            int row = rowb + (s << 5);
            size_t gi = (size_t)(row0 + row) * ZDIM + c * 32 + col4;
            float4 m4 = *reinterpret_cast<const float4*>(mean + gi);
            float4 l4 = *reinterpret_cast<const float4*>(logvar + gi);
            float4 e4 = *reinterpret_cast<const float4*>(eps + gi);
            float4 z4;
            z4.x = __builtin_fmaf(e4.x, __expf(0.5f * l4.x), m4.x);
            z4.y = __builtin_fmaf(e4.y, __expf(0.5f * l4.y), m4.y);
            z4.z = __builtin_fmaf(e4.z, __expf(0.5f * l4.z), m4.z);
            z4.w = __builtin_fmaf(e4.w, __expf(0.5f * l4.w), m4.w);
            *reinterpret_cast<float4*>(zs + row * SSTR + col4) = z4;
            float4 q4;
            q4.x = __builtin_fmaf(e4.x, e4.x, l4.x);
            q4.y = __builtin_fmaf(e4.y, e4.y, l4.y);
            q4.z = __builtin_fmaf(e4.z, e4.z, l4.z);
            q4.w = __builtin_fmaf(e4.w, e4.w, l4.w);
            q4s[s] = q4;
        }
        __syncthreads();
        if ((c & 1) == g) {                      // chunk owner reads its slice
            #pragma unroll
            for (int k4 = 0; k4 < 32; k4 += 4) {
                float4 v = *reinterpret_cast<const float4*>(zs + r * SSTR + k4);
                if (c < 2) { zA[k4] = v.x; zA[k4+1] = v.y; zA[k4+2] = v.z; zA[k4+3] = v.w; }
                else       { zB[k4] = v.x; zB[k4+1] = v.y; zB[k4+2] = v.z; zB[k4+3] = v.w; }
            }
        }
        __syncthreads();
        #pragma unroll
        for (int s = 0; s < 4; ++s) {
            int row = rowb + (s << 5);
            *reinterpret_cast<float4*>(zs + row * SSTR + col4) = q4s[s];
        }
        __syncthreads();
        if ((c & 1) == g) {
            #pragma unroll
            for (int k4 = 0; k4 < 32; k4 += 4) {
                float4 v = *reinterpret_cast<const float4*>(zs + r * SSTR + k4);
                qsum += (v.x + v.y) + (v.z + v.w);
            }
        }
        __syncthreads();
    }

    // ---- Phase B: 4 couplings ----
    float* hrow = smem + r * HSTR;
    float ld0 = 0.f, ld1 = 0.f, ld2 = 0.f, ld3 = 0.f;

    COUPLING(zA, zB, 0)   // flow 0, half 0: z1 conditions z2
    COUPLING(zB, zA, 1)   // flow 0, half 1: z2 conditions z1
    COUPLING(zA, zB, 2)   // flow 1, half 0
    COUPLING(zB, zA, 3)   // flow 1, half 1

    // partial logpz over this thread's 64 state values
    float p0 = 0.f, p1 = 0.f, p2 = 0.f, p3 = 0.f;
    #pragma unroll
    for (int j = 0; j < 32; j += 4) {
        p0 = __builtin_fmaf(zA[j + 0], zA[j + 0], p0);
        p1 = __builtin_fmaf(zA[j + 1], zA[j + 1], p1);
        p2 = __builtin_fmaf(zA[j + 2], zA[j + 2], p2);
        p3 = __builtin_fmaf(zA[j + 3], zA[j + 3], p3);
    }
    #pragma unroll
    for (int j = 0; j < 32; j += 4) {
        p0 = __builtin_fmaf(zB[j + 0], zB[j + 0], p0);
        p1 = __builtin_fmaf(zB[j + 1], zB[j + 1], p1);
        p2 = __builtin_fmaf(zB[j + 2], zB[j + 2], p2);
        p3 = __builtin_fmaf(zB[j + 3], zB[j + 3], p3);
    }
    const float ldp = (ld0 + ld1) + (ld2 + ld3);
    const float pp_ = (p0 + p1) + (p2 + p3);

    // ---- combine partner partials (g=1 -> LDS -> g=0) ----
    // (last COUPLING ended with __syncthreads, so hrow reuse is safe)
    if (g == 1) {
        float* cb = smem + r * 4;
        cb[0] = qsum; cb[1] = ldp; cb[2] = pp_;
    }
    __syncthreads();
    float logpz = 0.f, logqz = 0.f;
    if (g == 0) {
        const float* cb = smem + r * 4;
        float qs = qsum + cb[0];
        float lt = ldp  + cb[1];
        float pt = pp_  + cb[2];
        logqz = -0.5f * qs - lt;    // logqz0 - logdet
        logpz = -0.5f * pt;
    }

    // ---- Phase C: staging transpose back, float4 coalesced store of z ----
    #pragma unroll
    for (int c = 0; c < 4; ++c) {
        __syncthreads();
        if ((c & 1) == g) {
            #pragma unroll
            for (int k4 = 0; k4 < 32; k4 += 4) {
                float4 v;
                if (c < 2) { v.x = zA[k4]; v.y = zA[k4+1]; v.z = zA[k4+2]; v.w = zA[k4+3]; }
                else       { v.x = zB[k4]; v.y = zB[k4+1]; v.z = zB[k4+2]; v.w = zB[k4+3]; }
                *reinterpret_cast<float4*>(zs + r * SSTR + k4) = v;
            }
        }
        __syncthreads();
        #pragma unroll
        for (int s = 0; s < 4; ++s) {
            int row = rowb + (s << 5);
            float4 v = *reinterpret_cast<const float4*>(zs + row * SSTR + col4);
            *reinterpret_cast<float4*>(out + (size_t)(row0 + row) * ZDIM + c * 32 + col4) = v;
        }
    }
    const size_t zEnd = (size_t)B_ROWS * ZDIM;
    if (g == 0) {                  // tid 0..127, r == tid: coalesced stores
        out[zEnd + row0 + r]          = logpz;
        out[zEnd + B_ROWS + row0 + r] = logqz;
    }
}

extern "C" void kernel_launch(void* const* d_in, const int* in_sizes, int n_in,
                              void* d_out, int out_size, void* d_ws, size_t ws_size,
                              hipStream_t stream)
{
    const float* mean   = (const float*)d_in[0];
    const float* logvar = (const float*)d_in[1];
    const float* eps    = (const float*)d_in[2];
    const float* W_in   = (const float*)d_in[3];
    const float* b_in   = (const float*)d_in[4];
    const float* W_mu   = (const float*)d_in[5];
    const float* b_mu   = (const float*)d_in[6];
    const float* W_sig  = (const float*)d_in[7];
    const float* b_sig  = (const float*)d_in[8];
    float* out = (float*)d_out;
    float* wt  = (float*)d_ws;      // needs 2*12800*4 = 102400 B of scratch

    transpose_w<<<50, 256, 0, stream>>>(W_mu, W_sig, wt);
    flow_main<<<B_ROWS / RPB, 256, 0, stream>>>(mean, logvar, eps, W_in, b_in,
                                                b_mu, b_sig, wt, wt + 12800, out);
}